// Round 4
// baseline (609.728 us; speedup 1.0000x reference)
//
#include <hip/hip_runtime.h>
#include <hip/hip_bf16.h>

#define HW 128

typedef float f32x4 __attribute__((ext_vector_type(4)));
typedef short bf16x8 __attribute__((ext_vector_type(8)));

__device__ __forceinline__ unsigned short f2bf(float v) {
  __hip_bfloat16 h = __float2bfloat16(v);
  return *reinterpret_cast<unsigned short*>(&h);
}

__device__ __forceinline__ void bf8_to_f32(const int4& r, float* f) {
  const unsigned int* u = reinterpret_cast<const unsigned int*>(&r);
#pragma unroll
  for (int k = 0; k < 4; ++k) {
    f[2 * k]     = __uint_as_float(u[k] << 16);
    f[2 * k + 1] = __uint_as_float(u[k] & 0xffff0000u);
  }
}

__device__ __forceinline__ void gld_lds16(const void* g, void* l) {
  __builtin_amdgcn_global_load_lds(
      (const __attribute__((address_space(1))) void*)g,
      (__attribute__((address_space(3))) void*)l, 16, 0, 0);
}

// ---------------- k_prep: weight transposes ----------------
// wofft[(pos*18+oc)*64 + c] = w_off[oc][c][pos]                       (f32)
// wtbs[(t*64+o)*64 + ((c8^(o&7))*8) + cj] = bf16(w[o][c][t]), c=c8*8+cj  (chunk-swizzled, o-major)
__global__ __launch_bounds__(256) void k_prep(const float* __restrict__ w,
                                              const float* __restrict__ w_off,
                                              float* __restrict__ wofft,
                                              unsigned short* __restrict__ wtbs) {
  int i = blockIdx.x * 256 + threadIdx.x;
  if (i < 36864) {
    int o = i & 63, tc = i >> 6;
    int c = tc & 63, t = tc >> 6;
    float v = w[o * 576 + c * 9 + t];
    int c8 = c >> 3, cj = c & 7;
    wtbs[(t * 64 + o) * 64 + (((c8 ^ (o & 7)) << 3) + cj)] = f2bf(v);
  }
  if (i < 10368) {
    int c = i & 63, rem = i >> 6;
    int oc = rem % 18, pos = rem / 18;
    wofft[i] = w_off[oc * 576 + c * 9 + pos];
  }
}

// ---------------- k_tr: x NCHW f32 -> xt[b][h][w][c] bf16 ----------------
__global__ __launch_bounds__(256) void k_tr(const float* __restrict__ x,
                                            unsigned int* __restrict__ xt_u32) {
  __shared__ float tile[64 * 129];
  int blk = blockIdx.x;                   // b*128 + h
  int h = blk & 127, b = blk >> 7;
  int tid = threadIdx.x;
  int w0 = tid & 127, ch = tid >> 7;
  const float* xb = x + ((size_t)b * 64 * HW + h) * HW;
#pragma unroll
  for (int k = 0; k < 32; ++k) {
    int c = ch * 32 + k;
    tile[c * 129 + (w0 ^ (c & 1))] = xb[c * (HW * HW) + w0];
  }
  __syncthreads();
  int c2 = tid & 31, wg = tid >> 5;
#pragma unroll
  for (int k = 0; k < 16; ++k) {
    int ww = wg * 16 + k;
    float lo = tile[(2 * c2) * 129 + ww];
    float hi = tile[(2 * c2 + 1) * 129 + (ww ^ 1)];
    xt_u32[((b * HW + h) * HW + ww) * 32 + c2] =
        (unsigned int)f2bf(lo) | ((unsigned int)f2bf(hi) << 16);
  }
}

// ---------------- k_off: offsets conv -> offs[pixel][18] f32 ----------------
__global__ __launch_bounds__(256) void k_off(const unsigned short* __restrict__ xt,
                                             const float* __restrict__ wofft,
                                             const float* __restrict__ b_off,
                                             float* __restrict__ offs) {
  __shared__ __align__(16) float wsh[10368];
  for (int i = threadIdx.x; i < 2592; i += 256)
    *reinterpret_cast<float4*>(&wsh[i * 4]) = reinterpret_cast<const float4*>(wofft)[i];
  __syncthreads();

  int g = threadIdx.x & 7, p = threadIdx.x >> 3;
  int pix = blockIdx.x * 32 + p;
  int wx = pix & 127, h = (pix >> 7) & 127, b = pix >> 14;
  const unsigned short* xtb = xt + (size_t)b * (HW * HW * 64) + g * 8;

  float acc18[18];
#pragma unroll
  for (int oc = 0; oc < 18; ++oc) acc18[oc] = 0.f;

#pragma unroll
  for (int pos = 0; pos < 9; ++pos) {
    int y = h + pos / 3 - 1, xx = wx + pos % 3 - 1;
    bool ok = ((unsigned)y < HW) && ((unsigned)xx < HW);
    int4 raw = make_int4(0, 0, 0, 0);
    if (ok) raw = *reinterpret_cast<const int4*>(xtb + ((size_t)y * HW + xx) * 64);
    float xv[8];
    bf8_to_f32(raw, xv);
    const float* wr = &wsh[(pos * 18) * 64 + g * 8];
#pragma unroll
    for (int oc = 0; oc < 18; ++oc) {
      float4 wa = *reinterpret_cast<const float4*>(wr + oc * 64);
      float4 wb = *reinterpret_cast<const float4*>(wr + oc * 64 + 4);
      float s = acc18[oc];
      s = fmaf(xv[0], wa.x, s); s = fmaf(xv[1], wa.y, s);
      s = fmaf(xv[2], wa.z, s); s = fmaf(xv[3], wa.w, s);
      s = fmaf(xv[4], wb.x, s); s = fmaf(xv[5], wb.y, s);
      s = fmaf(xv[6], wb.z, s); s = fmaf(xv[7], wb.w, s);
      acc18[oc] = s;
    }
  }
#pragma unroll
  for (int oc = 0; oc < 18; ++oc) {
    float v = acc18[oc];
    v += __shfl_xor(v, 1);
    v += __shfl_xor(v, 2);
    v += __shfl_xor(v, 4);
    acc18[oc] = v;
  }
  offs[pix * 18 + g]     = acc18[g]     + b_off[g];
  offs[pix * 18 + 8 + g] = acc18[8 + g] + b_off[8 + g];
  if (g < 2) offs[pix * 18 + 16 + g] = acc18[16 + g] + b_off[16 + g];
}

// ---------------- k_gather: sampled[(loc*9+t)*64 + swz-chunk] bf16 ----------------
// logical chunk g stored at physical chunk g^(pix&7)  (pre-swizzled global, m173)
__global__ __launch_bounds__(256) void k_gather(const unsigned short* __restrict__ xt,
                                                const float* __restrict__ offs,
                                                unsigned short* __restrict__ sampled,
                                                int pix_base) {
  int tid = threadIdx.x;
  int g = tid & 7, p = tid >> 3;
  int t = blockIdx.y;
  int pix = pix_base + blockIdx.x * 32 + p;
  int wx = pix & 127, h = (pix >> 7) & 127, b = pix >> 14;
  const unsigned short* xtb = xt + (size_t)b * (HW * HW * 64) + g * 8;

  float2 d = *reinterpret_cast<const float2*>(&offs[pix * 18 + 2 * t]);
  float py = (float)(h + (t / 3) - 1) + d.x;
  float px = (float)(wx + (t % 3) - 1) + d.y;
  float y0f = floorf(py), x0f = floorf(px);
  float wy = py - y0f, wxf = px - x0f;
  int y0 = (int)y0f, x0 = (int)x0f;
  int y1 = y0 + 1, x1 = x0 + 1;
  float f00 = (((unsigned)y0 < HW) && ((unsigned)x0 < HW)) ? (1.f - wy) * (1.f - wxf) : 0.f;
  float f01 = (((unsigned)y0 < HW) && ((unsigned)x1 < HW)) ? (1.f - wy) * wxf : 0.f;
  float f10 = (((unsigned)y1 < HW) && ((unsigned)x0 < HW)) ? wy * (1.f - wxf) : 0.f;
  float f11 = (((unsigned)y1 < HW) && ((unsigned)x1 < HW)) ? wy * wxf : 0.f;
  int y0c = min(max(y0, 0), HW - 1), y1c = min(max(y1, 0), HW - 1);
  int x0c = min(max(x0, 0), HW - 1), x1c = min(max(x1, 0), HW - 1);

  int4 r00 = *reinterpret_cast<const int4*>(xtb + ((size_t)y0c * HW + x0c) * 64);
  int4 r01 = *reinterpret_cast<const int4*>(xtb + ((size_t)y0c * HW + x1c) * 64);
  int4 r10 = *reinterpret_cast<const int4*>(xtb + ((size_t)y1c * HW + x0c) * 64);
  int4 r11 = *reinterpret_cast<const int4*>(xtb + ((size_t)y1c * HW + x1c) * 64);
  float v00[8], v01[8], v10[8], v11[8];
  bf8_to_f32(r00, v00); bf8_to_f32(r01, v01);
  bf8_to_f32(r10, v10); bf8_to_f32(r11, v11);

  unsigned int pk[4];
#pragma unroll
  for (int j = 0; j < 4; ++j) {
    float slo = fmaf(v11[2 * j], f11, fmaf(v10[2 * j], f10, fmaf(v01[2 * j], f01, v00[2 * j] * f00)));
    float shi = fmaf(v11[2 * j + 1], f11, fmaf(v10[2 * j + 1], f10, fmaf(v01[2 * j + 1], f01, v00[2 * j + 1] * f00)));
    pk[j] = (unsigned int)f2bf(slo) | ((unsigned int)f2bf(shi) << 16);
  }
  int swz = (g ^ (pix & 7)) << 3;
  *reinterpret_cast<int4*>(&sampled[((size_t)(pix - pix_base) * 9 + t) * 64 + swz]) =
      *reinterpret_cast<int4*>(pk);
}

// ---------------- k_gemm: out[b][o][h][w] = sampled * wtbs + bias (MFMA) ----------------
__global__ __launch_bounds__(256) void k_gemm(const unsigned short* __restrict__ sampled,
                                              const unsigned short* __restrict__ wtbs,
                                              const float* __restrict__ bias,
                                              float* __restrict__ out,
                                              int pix_base) {
  __shared__ __align__(16) unsigned short ldsA[2][4096];
  __shared__ __align__(16) unsigned short ldsB[2][4096];
  int tid = threadIdx.x;
  int wid = tid >> 6, lane = tid & 63;
  int l15 = lane & 15, l4 = lane >> 4;
  int wm = wid >> 1, wn = wid & 1;
  int loc0 = blockIdx.x * 64;
  int pix0 = pix_base + loc0;

  f32x4 acc00 = {0.f, 0.f, 0.f, 0.f}, acc01 = {0.f, 0.f, 0.f, 0.f};
  f32x4 acc10 = {0.f, 0.f, 0.f, 0.f}, acc11 = {0.f, 0.f, 0.f, 0.f};

  auto stage = [&](int t, int bsel) {
#pragma unroll
    for (int j = 0; j < 2; ++j) {
      int instr = j * 4 + wid;
      int cg = instr * 64 + lane;
      int row = cg >> 3, c8 = cg & 7;
      gld_lds16(sampled + ((size_t)(loc0 + row) * 9 + t) * 64 + c8 * 8,
                &ldsA[bsel][instr * 512]);
      gld_lds16(wtbs + ((size_t)(t * 64 + row) * 64 + c8 * 8),
                &ldsB[bsel][instr * 512]);
    }
  };

  stage(0, 0);
#pragma unroll
  for (int t = 0; t < 9; ++t) {
    int cur = t & 1;
    if (t < 8) {
      stage(t + 1, cur ^ 1);
      asm volatile("s_waitcnt vmcnt(4)" ::: "memory");
    } else {
      asm volatile("s_waitcnt vmcnt(0)" ::: "memory");
    }
    __builtin_amdgcn_s_barrier();
    __builtin_amdgcn_sched_barrier(0);

    const char* Ab = (const char*)ldsA[cur];
    const char* Bb = (const char*)ldsB[cur];
#pragma unroll
    for (int kk = 0; kk < 2; ++kk) {
      int sw = (((kk * 4 + l4) ^ (l15 & 7)) << 4) + l15 * 128;
      bf16x8 a0 = *(const bf16x8*)(Ab + (wm * 32 + 0)  * 128 + sw);
      bf16x8 a1 = *(const bf16x8*)(Ab + (wm * 32 + 16) * 128 + sw);
      bf16x8 b0 = *(const bf16x8*)(Bb + (wn * 32 + 0)  * 128 + sw);
      bf16x8 b1 = *(const bf16x8*)(Bb + (wn * 32 + 16) * 128 + sw);
      acc00 = __builtin_amdgcn_mfma_f32_16x16x32_bf16(a0, b0, acc00, 0, 0, 0);
      acc01 = __builtin_amdgcn_mfma_f32_16x16x32_bf16(a0, b1, acc01, 0, 0, 0);
      acc10 = __builtin_amdgcn_mfma_f32_16x16x32_bf16(a1, b0, acc10, 0, 0, 0);
      acc11 = __builtin_amdgcn_mfma_f32_16x16x32_bf16(a1, b1, acc11, 0, 0, 0);
    }
    __builtin_amdgcn_sched_barrier(0);
    __builtin_amdgcn_s_barrier();
  }

  int m0 = wm * 32 + (l4 << 2);
#pragma unroll
  for (int fm = 0; fm < 2; ++fm) {
#pragma unroll
    for (int fn = 0; fn < 2; ++fn) {
      f32x4 a = (fm == 0) ? ((fn == 0) ? acc00 : acc01) : ((fn == 0) ? acc10 : acc11);
      int o = wn * 32 + fn * 16 + l15;
      int pix = pix0 + m0 + fm * 16;
      int b = pix >> 14, hw = pix & 16383;
      float bz = bias[o];
      float4 st = make_float4(a[0] + bz, a[1] + bz, a[2] + bz, a[3] + bz);
      *reinterpret_cast<float4*>(&out[(((size_t)b * 64 + o) << 14) + hw]) = st;
    }
  }
}

extern "C" void kernel_launch(void* const* d_in, const int* in_sizes, int n_in,
                              void* d_out, int out_size, void* d_ws, size_t ws_size,
                              hipStream_t stream) {
  const float* x     = (const float*)d_in[0];
  const float* w_off = (const float*)d_in[1];
  const float* b_off = (const float*)d_in[2];
  const float* w     = (const float*)d_in[3];
  const float* bias  = (const float*)d_in[4];
  float* out = (float*)d_out;
  char* ws   = (char*)d_ws;

  // ws layout (BYTES):
  //   wofft   [0,          41,472)
  //   wtbs    [41,472,     115,200)      36,864 bf16
  //   offs    [115,200,    4,833,792)    65,536 * 18 f32
  //   xt      [4,833,792,  13,222,400)   4,194,304 bf16 = 8,388,608 B  (was the r3 bug: sized in elems)
  //   sampled [13,222,400, ...)          npix * 9 * 64 bf16
  float*          wofft   = (float*)(ws);
  unsigned short* wtbs    = (unsigned short*)(ws + 41472);
  float*          offs    = (float*)(ws + 115200);
  unsigned short* xt      = (unsigned short*)(ws + 4833792);
  unsigned short* sampled = (unsigned short*)(ws + 13222400);

  const size_t fixed_bytes = 13222400;
  const size_t samp_bytes  = 75497472;  // 65536*9*64*2
  int S = 1;
  while (S < 64 && fixed_bytes + samp_bytes / (size_t)S > ws_size) S <<= 1;
  int npix = 65536 / S;

  hipLaunchKernelGGL(k_prep, dim3(144),  dim3(256), 0, stream, w, w_off, wofft, wtbs);
  hipLaunchKernelGGL(k_tr,   dim3(512),  dim3(256), 0, stream, x, (unsigned int*)xt);
  hipLaunchKernelGGL(k_off,  dim3(2048), dim3(256), 0, stream, xt, wofft, b_off, offs);
  for (int s = 0; s < S; ++s) {
    int pb = s * npix;
    hipLaunchKernelGGL(k_gather, dim3(npix / 32, 9), dim3(256), 0, stream, xt, offs, sampled, pb);
    hipLaunchKernelGGL(k_gemm,   dim3(npix / 64),    dim3(256), 0, stream, sampled, wtbs, bias, out, pb);
  }
}

// Round 5
// 127.031 us; speedup vs baseline: 4.7998x; 4.7998x over previous
//
#include <hip/hip_runtime.h>
#include <hip/hip_bf16.h>

#define HW 128

typedef float f32x4 __attribute__((ext_vector_type(4)));
typedef short bf16x8 __attribute__((ext_vector_type(8)));

__device__ __forceinline__ unsigned short f2bf(float v) {
  __hip_bfloat16 h = __float2bfloat16(v);
  return *reinterpret_cast<unsigned short*>(&h);
}

__device__ __forceinline__ void bf8_to_f32(const int4& r, float* f) {
  const unsigned int* u = reinterpret_cast<const unsigned int*>(&r);
#pragma unroll
  for (int k = 0; k < 4; ++k) {
    f[2 * k]     = __uint_as_float(u[k] << 16);
    f[2 * k + 1] = __uint_as_float(u[k] & 0xffff0000u);
  }
}

__device__ __forceinline__ void gld_lds16(const void* g, void* l) {
  __builtin_amdgcn_global_load_lds(
      (const __attribute__((address_space(1))) void*)g,
      (__attribute__((address_space(3))) void*)l, 16, 0, 0);
}

// ---------------- k_prep: weight transposes ----------------
// wofft[(pos*18+oc)*64 + c] = w_off[oc][c][pos]                       (f32)
// wtbs[(t*64+o)*64 + ((c8^(o&7))*8) + cj] = bf16(w[o][c][t]), c=c8*8+cj  (chunk-swizzled, o-major)
__global__ __launch_bounds__(256) void k_prep(const float* __restrict__ w,
                                              const float* __restrict__ w_off,
                                              float* __restrict__ wofft,
                                              unsigned short* __restrict__ wtbs) {
  int i = blockIdx.x * 256 + threadIdx.x;
  if (i < 36864) {
    int o = i & 63, tc = i >> 6;
    int c = tc & 63, t = tc >> 6;
    float v = w[o * 576 + c * 9 + t];
    int c8 = c >> 3, cj = c & 7;
    wtbs[(t * 64 + o) * 64 + (((c8 ^ (o & 7)) << 3) + cj)] = f2bf(v);
  }
  if (i < 10368) {
    int c = i & 63, rem = i >> 6;
    int oc = rem % 18, pos = rem / 18;
    wofft[i] = w_off[oc * 576 + c * 9 + pos];
  }
}

// ---------------- k_tr: x NCHW f32 -> xt[b][h][w][c] bf16 ----------------
__global__ __launch_bounds__(256) void k_tr(const float* __restrict__ x,
                                            unsigned int* __restrict__ xt_u32) {
  __shared__ float tile[64 * 129];
  int blk = blockIdx.x;                   // b*128 + h
  int h = blk & 127, b = blk >> 7;
  int tid = threadIdx.x;
  int w0 = tid & 127, ch = tid >> 7;
  const float* xb = x + ((size_t)b * 64 * HW + h) * HW;
#pragma unroll
  for (int k = 0; k < 32; ++k) {
    int c = ch * 32 + k;
    tile[c * 129 + (w0 ^ (c & 1))] = xb[c * (HW * HW) + w0];
  }
  __syncthreads();
  int c2 = tid & 31, wg = tid >> 5;
#pragma unroll
  for (int k = 0; k < 16; ++k) {
    int ww = wg * 16 + k;
    float lo = tile[(2 * c2) * 129 + ww];
    float hi = tile[(2 * c2 + 1) * 129 + (ww ^ 1)];
    xt_u32[((b * HW + h) * HW + ww) * 32 + c2] =
        (unsigned int)f2bf(lo) | ((unsigned int)f2bf(hi) << 16);
  }
}

// ---------------- k_off: offsets conv -> offs[pixel][18] f32 ----------------
// r2-proven shape: global wofft reads (8 distinct float4/wave, L1-resident),
// NO unroll on pos loop (unrolling -> 324 live float4 -> 2.7KB/thread scratch spill, r4).
__global__ __launch_bounds__(256) void k_off(const unsigned short* __restrict__ xt,
                                             const float* __restrict__ wofft,
                                             const float* __restrict__ b_off,
                                             float* __restrict__ offs) {
  int g = threadIdx.x & 7, p = threadIdx.x >> 3;
  int pix = blockIdx.x * 32 + p;
  int wx = pix & 127, h = (pix >> 7) & 127, b = pix >> 14;
  const unsigned short* xtb = xt + (size_t)b * (HW * HW * 64) + g * 8;

  float acc18[18];
#pragma unroll
  for (int oc = 0; oc < 18; ++oc) acc18[oc] = 0.f;

  for (int pos = 0; pos < 9; ++pos) {   // intentionally NOT unrolled
    int y = h + pos / 3 - 1, xx = wx + pos % 3 - 1;
    bool ok = ((unsigned)y < HW) && ((unsigned)xx < HW);
    int4 raw = make_int4(0, 0, 0, 0);
    if (ok) raw = *reinterpret_cast<const int4*>(xtb + ((size_t)y * HW + xx) * 64);
    float xv[8];
    bf8_to_f32(raw, xv);
    const float* wr = wofft + pos * 18 * 64 + g * 8;
#pragma unroll
    for (int oc = 0; oc < 18; ++oc) {
      float4 wa = *reinterpret_cast<const float4*>(wr + oc * 64);
      float4 wb = *reinterpret_cast<const float4*>(wr + oc * 64 + 4);
      float s = acc18[oc];
      s = fmaf(xv[0], wa.x, s); s = fmaf(xv[1], wa.y, s);
      s = fmaf(xv[2], wa.z, s); s = fmaf(xv[3], wa.w, s);
      s = fmaf(xv[4], wb.x, s); s = fmaf(xv[5], wb.y, s);
      s = fmaf(xv[6], wb.z, s); s = fmaf(xv[7], wb.w, s);
      acc18[oc] = s;
    }
  }
#pragma unroll
  for (int oc = 0; oc < 18; ++oc) {
    float v = acc18[oc];
    v += __shfl_xor(v, 1);
    v += __shfl_xor(v, 2);
    v += __shfl_xor(v, 4);
    acc18[oc] = v;
  }
  offs[pix * 18 + g]     = acc18[g]     + b_off[g];
  offs[pix * 18 + 8 + g] = acc18[8 + g] + b_off[8 + g];
  if (g < 2) offs[pix * 18 + 16 + g] = acc18[16 + g] + b_off[16 + g];
}

// ---------------- k_gather: sampled[(loc*9+t)*64 + swz-chunk] bf16 ----------------
// logical chunk g stored at physical chunk g^(pix&7)  (pre-swizzled global, m173)
__global__ __launch_bounds__(256) void k_gather(const unsigned short* __restrict__ xt,
                                                const float* __restrict__ offs,
                                                unsigned short* __restrict__ sampled,
                                                int pix_base) {
  int tid = threadIdx.x;
  int g = tid & 7, p = tid >> 3;
  int t = blockIdx.y;
  int pix = pix_base + blockIdx.x * 32 + p;
  int wx = pix & 127, h = (pix >> 7) & 127, b = pix >> 14;
  const unsigned short* xtb = xt + (size_t)b * (HW * HW * 64) + g * 8;

  float2 d = *reinterpret_cast<const float2*>(&offs[pix * 18 + 2 * t]);
  float py = (float)(h + (t / 3) - 1) + d.x;
  float px = (float)(wx + (t % 3) - 1) + d.y;
  float y0f = floorf(py), x0f = floorf(px);
  float wy = py - y0f, wxf = px - x0f;
  int y0 = (int)y0f, x0 = (int)x0f;
  int y1 = y0 + 1, x1 = x0 + 1;
  float f00 = (((unsigned)y0 < HW) && ((unsigned)x0 < HW)) ? (1.f - wy) * (1.f - wxf) : 0.f;
  float f01 = (((unsigned)y0 < HW) && ((unsigned)x1 < HW)) ? (1.f - wy) * wxf : 0.f;
  float f10 = (((unsigned)y1 < HW) && ((unsigned)x0 < HW)) ? wy * (1.f - wxf) : 0.f;
  float f11 = (((unsigned)y1 < HW) && ((unsigned)x1 < HW)) ? wy * wxf : 0.f;
  int y0c = min(max(y0, 0), HW - 1), y1c = min(max(y1, 0), HW - 1);
  int x0c = min(max(x0, 0), HW - 1), x1c = min(max(x1, 0), HW - 1);

  int4 r00 = *reinterpret_cast<const int4*>(xtb + ((size_t)y0c * HW + x0c) * 64);
  int4 r01 = *reinterpret_cast<const int4*>(xtb + ((size_t)y0c * HW + x1c) * 64);
  int4 r10 = *reinterpret_cast<const int4*>(xtb + ((size_t)y1c * HW + x0c) * 64);
  int4 r11 = *reinterpret_cast<const int4*>(xtb + ((size_t)y1c * HW + x1c) * 64);
  float v00[8], v01[8], v10[8], v11[8];
  bf8_to_f32(r00, v00); bf8_to_f32(r01, v01);
  bf8_to_f32(r10, v10); bf8_to_f32(r11, v11);

  unsigned int pk[4];
#pragma unroll
  for (int j = 0; j < 4; ++j) {
    float slo = fmaf(v11[2 * j], f11, fmaf(v10[2 * j], f10, fmaf(v01[2 * j], f01, v00[2 * j] * f00)));
    float shi = fmaf(v11[2 * j + 1], f11, fmaf(v10[2 * j + 1], f10, fmaf(v01[2 * j + 1], f01, v00[2 * j + 1] * f00)));
    pk[j] = (unsigned int)f2bf(slo) | ((unsigned int)f2bf(shi) << 16);
  }
  int swz = (g ^ (pix & 7)) << 3;
  *reinterpret_cast<int4*>(&sampled[((size_t)(pix - pix_base) * 9 + t) * 64 + swz]) =
      *reinterpret_cast<int4*>(pk);
}

// ---------------- k_gemm: out[b][o][h][w] = sampled * wtbs + bias (MFMA) ----------------
__global__ __launch_bounds__(256) void k_gemm(const unsigned short* __restrict__ sampled,
                                              const unsigned short* __restrict__ wtbs,
                                              const float* __restrict__ bias,
                                              float* __restrict__ out,
                                              int pix_base) {
  __shared__ __align__(16) unsigned short ldsA[2][4096];
  __shared__ __align__(16) unsigned short ldsB[2][4096];
  int tid = threadIdx.x;
  int wid = tid >> 6, lane = tid & 63;
  int l15 = lane & 15, l4 = lane >> 4;
  int wm = wid >> 1, wn = wid & 1;
  int loc0 = blockIdx.x * 64;
  int pix0 = pix_base + loc0;

  f32x4 acc00 = {0.f, 0.f, 0.f, 0.f}, acc01 = {0.f, 0.f, 0.f, 0.f};
  f32x4 acc10 = {0.f, 0.f, 0.f, 0.f}, acc11 = {0.f, 0.f, 0.f, 0.f};

  auto stage = [&](int t, int bsel) {
#pragma unroll
    for (int j = 0; j < 2; ++j) {
      int instr = j * 4 + wid;
      int cg = instr * 64 + lane;
      int row = cg >> 3, c8 = cg & 7;
      gld_lds16(sampled + ((size_t)(loc0 + row) * 9 + t) * 64 + c8 * 8,
                &ldsA[bsel][instr * 512]);
      gld_lds16(wtbs + ((size_t)(t * 64 + row) * 64 + c8 * 8),
                &ldsB[bsel][instr * 512]);
    }
  };

  stage(0, 0);
#pragma unroll
  for (int t = 0; t < 9; ++t) {
    int cur = t & 1;
    if (t < 8) {
      stage(t + 1, cur ^ 1);
      asm volatile("s_waitcnt vmcnt(4)" ::: "memory");
    } else {
      asm volatile("s_waitcnt vmcnt(0)" ::: "memory");
    }
    __builtin_amdgcn_s_barrier();
    __builtin_amdgcn_sched_barrier(0);

    const char* Ab = (const char*)ldsA[cur];
    const char* Bb = (const char*)ldsB[cur];
#pragma unroll
    for (int kk = 0; kk < 2; ++kk) {
      int sw = (((kk * 4 + l4) ^ (l15 & 7)) << 4) + l15 * 128;
      bf16x8 a0 = *(const bf16x8*)(Ab + (wm * 32 + 0)  * 128 + sw);
      bf16x8 a1 = *(const bf16x8*)(Ab + (wm * 32 + 16) * 128 + sw);
      bf16x8 b0 = *(const bf16x8*)(Bb + (wn * 32 + 0)  * 128 + sw);
      bf16x8 b1 = *(const bf16x8*)(Bb + (wn * 32 + 16) * 128 + sw);
      acc00 = __builtin_amdgcn_mfma_f32_16x16x32_bf16(a0, b0, acc00, 0, 0, 0);
      acc01 = __builtin_amdgcn_mfma_f32_16x16x32_bf16(a0, b1, acc01, 0, 0, 0);
      acc10 = __builtin_amdgcn_mfma_f32_16x16x32_bf16(a1, b0, acc10, 0, 0, 0);
      acc11 = __builtin_amdgcn_mfma_f32_16x16x32_bf16(a1, b1, acc11, 0, 0, 0);
    }
    __builtin_amdgcn_sched_barrier(0);
    __builtin_amdgcn_s_barrier();
  }

  int m0 = wm * 32 + (l4 << 2);
#pragma unroll
  for (int fm = 0; fm < 2; ++fm) {
#pragma unroll
    for (int fn = 0; fn < 2; ++fn) {
      f32x4 a = (fm == 0) ? ((fn == 0) ? acc00 : acc01) : ((fn == 0) ? acc10 : acc11);
      int o = wn * 32 + fn * 16 + l15;
      int pix = pix0 + m0 + fm * 16;
      int b = pix >> 14, hw = pix & 16383;
      float bz = bias[o];
      float4 st = make_float4(a[0] + bz, a[1] + bz, a[2] + bz, a[3] + bz);
      *reinterpret_cast<float4*>(&out[(((size_t)b * 64 + o) << 14) + hw]) = st;
    }
  }
}

extern "C" void kernel_launch(void* const* d_in, const int* in_sizes, int n_in,
                              void* d_out, int out_size, void* d_ws, size_t ws_size,
                              hipStream_t stream) {
  const float* x     = (const float*)d_in[0];
  const float* w_off = (const float*)d_in[1];
  const float* b_off = (const float*)d_in[2];
  const float* w     = (const float*)d_in[3];
  const float* bias  = (const float*)d_in[4];
  float* out = (float*)d_out;
  char* ws   = (char*)d_ws;

  // ws layout (BYTES):
  //   wofft   [0,          41,472)
  //   wtbs    [41,472,     115,200)      36,864 bf16
  //   offs    [115,200,    4,833,792)    65,536 * 18 f32
  //   xt      [4,833,792,  13,222,400)   4,194,304 bf16 = 8,388,608 B
  //   sampled [13,222,400, ...)          npix * 9 * 64 bf16
  float*          wofft   = (float*)(ws);
  unsigned short* wtbs    = (unsigned short*)(ws + 41472);
  float*          offs    = (float*)(ws + 115200);
  unsigned short* xt      = (unsigned short*)(ws + 4833792);
  unsigned short* sampled = (unsigned short*)(ws + 13222400);

  const size_t fixed_bytes = 13222400;
  const size_t samp_bytes  = 75497472;  // 65536*9*64*2
  int S = 1;
  while (S < 64 && fixed_bytes + samp_bytes / (size_t)S > ws_size) S <<= 1;
  int npix = 65536 / S;

  hipLaunchKernelGGL(k_prep, dim3(144),  dim3(256), 0, stream, w, w_off, wofft, wtbs);
  hipLaunchKernelGGL(k_tr,   dim3(512),  dim3(256), 0, stream, x, (unsigned int*)xt);
  hipLaunchKernelGGL(k_off,  dim3(2048), dim3(256), 0, stream, xt, wofft, b_off, offs);
  for (int s = 0; s < S; ++s) {
    int pb = s * npix;
    hipLaunchKernelGGL(k_gather, dim3(npix / 32, 9), dim3(256), 0, stream, xt, offs, sampled, pb);
    hipLaunchKernelGGL(k_gemm,   dim3(npix / 64),    dim3(256), 0, stream, sampled, wtbs, bias, out, pb);
  }
}

// Round 6
// 79.544 us; speedup vs baseline: 7.6653x; 1.5970x over previous
//
#include <hip/hip_runtime.h>
#include <hip/hip_bf16.h>

#define HW 128

typedef float f32x4 __attribute__((ext_vector_type(4)));
typedef short bf16x8 __attribute__((ext_vector_type(8)));

__device__ __forceinline__ unsigned short f2bf(float v) {
  __hip_bfloat16 h = __float2bfloat16(v);
  return *reinterpret_cast<unsigned short*>(&h);
}

__device__ __forceinline__ void bf8_to_f32(const int4& r, float* f) {
  const unsigned int* u = reinterpret_cast<const unsigned int*>(&r);
#pragma unroll
  for (int k = 0; k < 4; ++k) {
    f[2 * k]     = __uint_as_float(u[k] << 16);
    f[2 * k + 1] = __uint_as_float(u[k] & 0xffff0000u);
  }
}

__device__ __forceinline__ void gld_lds16(const void* g, void* l) {
  __builtin_amdgcn_global_load_lds(
      (const __attribute__((address_space(1))) void*)g,
      (__attribute__((address_space(3))) void*)l, 16, 0, 0);
}

// ---------------- k_prep: weight transposes ----------------
// wofft[(pos*18+oc)*64 + c] = w_off[oc][c][pos]                       (f32)
// wtbs[(t*64+o)*64 + ((c8^(o&7))*8) + cj] = bf16(w[o][c][t])          (chunk-swizzled, o-major)
__global__ __launch_bounds__(256) void k_prep(const float* __restrict__ w,
                                              const float* __restrict__ w_off,
                                              float* __restrict__ wofft,
                                              unsigned short* __restrict__ wtbs) {
  int i = blockIdx.x * 256 + threadIdx.x;
  if (i < 36864) {
    int o = i & 63, tc = i >> 6;
    int c = tc & 63, t = tc >> 6;
    float v = w[o * 576 + c * 9 + t];
    int c8 = c >> 3, cj = c & 7;
    wtbs[(t * 64 + o) * 64 + (((c8 ^ (o & 7)) << 3) + cj)] = f2bf(v);
  }
  if (i < 10368) {
    int c = i & 63, rem = i >> 6;
    int oc = rem % 18, pos = rem / 18;
    wofft[i] = w_off[oc * 576 + c * 9 + pos];
  }
}

// ---------------- k_tr: x NCHW f32 -> xt[b][h][w][c] bf16 ----------------
__global__ __launch_bounds__(256) void k_tr(const float* __restrict__ x,
                                            unsigned int* __restrict__ xt_u32) {
  __shared__ float tile[64 * 129];
  int blk = blockIdx.x;                   // b*128 + h
  int h = blk & 127, b = blk >> 7;
  int tid = threadIdx.x;
  int w0 = tid & 127, ch = tid >> 7;
  const float* xb = x + ((size_t)b * 64 * HW + h) * HW;
#pragma unroll
  for (int k = 0; k < 32; ++k) {
    int c = ch * 32 + k;
    tile[c * 129 + (w0 ^ (c & 1))] = xb[c * (HW * HW) + w0];
  }
  __syncthreads();
  int c2 = tid & 31, wg = tid >> 5;
#pragma unroll
  for (int k = 0; k < 16; ++k) {
    int ww = wg * 16 + k;
    float lo = tile[(2 * c2) * 129 + ww];
    float hi = tile[(2 * c2 + 1) * 129 + (ww ^ 1)];
    xt_u32[((b * HW + h) * HW + ww) * 32 + c2] =
        (unsigned int)f2bf(lo) | ((unsigned int)f2bf(hi) << 16);
  }
}

// ---------------- k_off: offsets conv -> offs[pixel][18] f32 ----------------
// Weights staged in LDS (r5 showed global weight reloads = L1-bound, 84us).
// pos loop MUST stay rolled (r4: unroll -> 324 live float4 -> scratch spill).
__global__ __launch_bounds__(256) void k_off(const unsigned short* __restrict__ xt,
                                             const float* __restrict__ wofft,
                                             const float* __restrict__ b_off,
                                             float* __restrict__ offs) {
  __shared__ __align__(16) float wsh[10368];
  for (int i = threadIdx.x; i < 2592; i += 256)
    *reinterpret_cast<float4*>(&wsh[i * 4]) = reinterpret_cast<const float4*>(wofft)[i];
  __syncthreads();

  int bid = blockIdx.x;
  bid = (bid & 7) * 256 + (bid >> 3);     // XCD swizzle (2048 % 8 == 0)
  int g = threadIdx.x & 7, p = threadIdx.x >> 3;
  int pix = bid * 32 + p;
  int wx = pix & 127, h = (pix >> 7) & 127, b = pix >> 14;
  const unsigned short* xtb = xt + (size_t)b * (HW * HW * 64) + g * 8;

  float acc18[18];
#pragma unroll
  for (int oc = 0; oc < 18; ++oc) acc18[oc] = 0.f;

#pragma unroll 1
  for (int pos = 0; pos < 9; ++pos) {     // intentionally NOT unrolled
    int y = h + pos / 3 - 1, xx = wx + pos % 3 - 1;
    bool ok = ((unsigned)y < HW) && ((unsigned)xx < HW);
    int4 raw = make_int4(0, 0, 0, 0);
    if (ok) raw = *reinterpret_cast<const int4*>(xtb + ((size_t)y * HW + xx) * 64);
    float xv[8];
    bf8_to_f32(raw, xv);
    const float* wr = &wsh[(pos * 18) * 64 + g * 8];
#pragma unroll
    for (int oc = 0; oc < 18; ++oc) {
      float4 wa = *reinterpret_cast<const float4*>(wr + oc * 64);
      float4 wb = *reinterpret_cast<const float4*>(wr + oc * 64 + 4);
      float s = acc18[oc];
      s = fmaf(xv[0], wa.x, s); s = fmaf(xv[1], wa.y, s);
      s = fmaf(xv[2], wa.z, s); s = fmaf(xv[3], wa.w, s);
      s = fmaf(xv[4], wb.x, s); s = fmaf(xv[5], wb.y, s);
      s = fmaf(xv[6], wb.z, s); s = fmaf(xv[7], wb.w, s);
      acc18[oc] = s;
    }
  }
#pragma unroll
  for (int oc = 0; oc < 18; ++oc) {
    float v = acc18[oc];
    v += __shfl_xor(v, 1);
    v += __shfl_xor(v, 2);
    v += __shfl_xor(v, 4);
    acc18[oc] = v;
  }
  offs[pix * 18 + g]     = acc18[g]     + b_off[g];
  offs[pix * 18 + 8 + g] = acc18[8 + g] + b_off[8 + g];
  if (g < 2) offs[pix * 18 + 16 + g] = acc18[16 + g] + b_off[16 + g];
}

// ---------------- k_fuse: gather + MFMA GEMM, no sampled round-trip ----------------
// Block = 64 pixels (one b,h, half-row). A-tile built in LDS by the gather
// (write: logical chunk g -> phys g^(pix&7), matching the read side).
// B staged via global_load_lds dbuf. Per tap: issue t+1 corner loads -> MFMA t
// -> lerp+ds_write t+1 -> vmcnt(0) -> barrier (T14 split).
__global__ __launch_bounds__(256) void k_fuse(const unsigned short* __restrict__ xt,
                                              const float* __restrict__ offs,
                                              const unsigned short* __restrict__ wtbs,
                                              const float* __restrict__ bias,
                                              float* __restrict__ out) {
  __shared__ __align__(16) unsigned short ldsA[2][4096];
  __shared__ __align__(16) unsigned short ldsB[2][4096];
  __shared__ __align__(16) float loff[64 * 18];

  int bid = blockIdx.x;
  bid = (bid & 7) * 128 + (bid >> 3);     // XCD swizzle (1024 % 8 == 0)
  int pix0 = bid * 64;
  int h = (pix0 >> 7) & 127, b = pix0 >> 14, wbase = pix0 & 127;

  int tid = threadIdx.x;
  int wid = tid >> 6, lane = tid & 63;
  int l15 = lane & 15, l4 = lane >> 4;
  int wm = wid >> 1, wn = wid & 1;
  int g = tid & 7, p2 = tid >> 3;         // gather: chunk g, pixels p2 and p2+32

  // stage offs for this block's 64 pixels (1152 floats, coalesced)
  for (int i = tid; i < 288; i += 256)
    reinterpret_cast<float4*>(loff)[i] =
        reinterpret_cast<const float4*>(offs + (size_t)pix0 * 18)[i];

  const unsigned short* xtb = xt + (size_t)b * (HW * HW * 64) + g * 8;

  auto stageB = [&](int t, int bsel) {
#pragma unroll
    for (int j = 0; j < 2; ++j) {
      int instr = j * 4 + wid;
      int cg = instr * 64 + lane;
      int row = cg >> 3, c8 = cg & 7;
      gld_lds16(wtbs + ((size_t)(t * 64 + row) * 64 + c8 * 8),
                &ldsB[bsel][instr * 512]);
    }
  };

  int4 r[2][4];        // [task][corner]
  float fw[2][4];      // lerp weights

  auto issue_gather = [&](int t) {
    int ti = t / 3, tj = t % 3;
#pragma unroll
    for (int k = 0; k < 2; ++k) {
      int pp = p2 + 32 * k;
      float2 d = *reinterpret_cast<const float2*>(&loff[pp * 18 + 2 * t]);
      float py = (float)(h + ti - 1) + d.x;
      float px = (float)(wbase + pp + tj - 1) + d.y;
      float y0f = floorf(py), x0f = floorf(px);
      float wy = py - y0f, wxf = px - x0f;
      int y0 = (int)y0f, x0 = (int)x0f;
      int y1 = y0 + 1, x1 = x0 + 1;
      fw[k][0] = (((unsigned)y0 < HW) && ((unsigned)x0 < HW)) ? (1.f - wy) * (1.f - wxf) : 0.f;
      fw[k][1] = (((unsigned)y0 < HW) && ((unsigned)x1 < HW)) ? (1.f - wy) * wxf : 0.f;
      fw[k][2] = (((unsigned)y1 < HW) && ((unsigned)x0 < HW)) ? wy * (1.f - wxf) : 0.f;
      fw[k][3] = (((unsigned)y1 < HW) && ((unsigned)x1 < HW)) ? wy * wxf : 0.f;
      int y0c = min(max(y0, 0), HW - 1), y1c = min(max(y1, 0), HW - 1);
      int x0c = min(max(x0, 0), HW - 1), x1c = min(max(x1, 0), HW - 1);
      r[k][0] = *reinterpret_cast<const int4*>(xtb + ((size_t)y0c * HW + x0c) * 64);
      r[k][1] = *reinterpret_cast<const int4*>(xtb + ((size_t)y0c * HW + x1c) * 64);
      r[k][2] = *reinterpret_cast<const int4*>(xtb + ((size_t)y1c * HW + x0c) * 64);
      r[k][3] = *reinterpret_cast<const int4*>(xtb + ((size_t)y1c * HW + x1c) * 64);
    }
  };

  auto lerp_write = [&](int bsel) {
#pragma unroll
    for (int k = 0; k < 2; ++k) {
      int pp = p2 + 32 * k;
      float v00[8], v01[8], v10[8], v11[8];
      bf8_to_f32(r[k][0], v00); bf8_to_f32(r[k][1], v01);
      bf8_to_f32(r[k][2], v10); bf8_to_f32(r[k][3], v11);
      unsigned int pk[4];
#pragma unroll
      for (int j = 0; j < 4; ++j) {
        float slo = fmaf(v11[2 * j], fw[k][3],
                    fmaf(v10[2 * j], fw[k][2],
                    fmaf(v01[2 * j], fw[k][1], v00[2 * j] * fw[k][0])));
        float shi = fmaf(v11[2 * j + 1], fw[k][3],
                    fmaf(v10[2 * j + 1], fw[k][2],
                    fmaf(v01[2 * j + 1], fw[k][1], v00[2 * j + 1] * fw[k][0])));
        pk[j] = (unsigned int)f2bf(slo) | ((unsigned int)f2bf(shi) << 16);
      }
      *reinterpret_cast<int4*>(&ldsA[bsel][pp * 64 + ((g ^ (pp & 7)) << 3)]) =
          *reinterpret_cast<int4*>(pk);
    }
  };

  f32x4 acc00 = {0.f, 0.f, 0.f, 0.f}, acc01 = {0.f, 0.f, 0.f, 0.f};
  f32x4 acc10 = {0.f, 0.f, 0.f, 0.f}, acc11 = {0.f, 0.f, 0.f, 0.f};

  // prologue
  __syncthreads();                 // loff ready
  stageB(0, 0);
  issue_gather(0);
  lerp_write(0);
  asm volatile("s_waitcnt vmcnt(0)" ::: "memory");
  __syncthreads();                 // A0, B0 ready

#pragma unroll 1
  for (int t = 0; t < 9; ++t) {
    int cur = t & 1;
    if (t < 8) {
      stageB(t + 1, cur ^ 1);
      issue_gather(t + 1);         // corner loads in flight under MFMA
    }
    const char* Ab = (const char*)ldsA[cur];
    const char* Bb = (const char*)ldsB[cur];
#pragma unroll
    for (int kk = 0; kk < 2; ++kk) {
      int sw = (((kk * 4 + l4) ^ (l15 & 7)) << 4) + l15 * 128;
      bf16x8 a0 = *(const bf16x8*)(Ab + (wm * 32 + 0)  * 128 + sw);
      bf16x8 a1 = *(const bf16x8*)(Ab + (wm * 32 + 16) * 128 + sw);
      bf16x8 b0 = *(const bf16x8*)(Bb + (wn * 32 + 0)  * 128 + sw);
      bf16x8 b1 = *(const bf16x8*)(Bb + (wn * 32 + 16) * 128 + sw);
      acc00 = __builtin_amdgcn_mfma_f32_16x16x32_bf16(a0, b0, acc00, 0, 0, 0);
      acc01 = __builtin_amdgcn_mfma_f32_16x16x32_bf16(a0, b1, acc01, 0, 0, 0);
      acc10 = __builtin_amdgcn_mfma_f32_16x16x32_bf16(a1, b0, acc10, 0, 0, 0);
      acc11 = __builtin_amdgcn_mfma_f32_16x16x32_bf16(a1, b1, acc11, 0, 0, 0);
    }
    if (t < 8) lerp_write(cur ^ 1);
    asm volatile("s_waitcnt vmcnt(0)" ::: "memory");
    __syncthreads();
  }

  // epilogue (layout verified in r5's k_gemm)
  int m0 = wm * 32 + (l4 << 2);
#pragma unroll
  for (int fm = 0; fm < 2; ++fm) {
#pragma unroll
    for (int fn = 0; fn < 2; ++fn) {
      f32x4 a = (fm == 0) ? ((fn == 0) ? acc00 : acc01) : ((fn == 0) ? acc10 : acc11);
      int o = wn * 32 + fn * 16 + l15;
      int pix = pix0 + m0 + fm * 16;
      int bb = pix >> 14, hw = pix & 16383;
      float bz = bias[o];
      float4 st = make_float4(a[0] + bz, a[1] + bz, a[2] + bz, a[3] + bz);
      *reinterpret_cast<float4*>(&out[(((size_t)bb * 64 + o) << 14) + hw]) = st;
    }
  }
}

extern "C" void kernel_launch(void* const* d_in, const int* in_sizes, int n_in,
                              void* d_out, int out_size, void* d_ws, size_t ws_size,
                              hipStream_t stream) {
  const float* x     = (const float*)d_in[0];
  const float* w_off = (const float*)d_in[1];
  const float* b_off = (const float*)d_in[2];
  const float* w     = (const float*)d_in[3];
  const float* bias  = (const float*)d_in[4];
  float* out = (float*)d_out;
  char* ws   = (char*)d_ws;

  // ws layout (BYTES):
  //   wofft [0,          41,472)
  //   wtbs  [41,472,     115,200)      36,864 bf16
  //   offs  [115,200,    4,833,792)    65,536 * 18 f32
  //   xt    [4,833,792,  13,222,400)   4,194,304 bf16 = 8,388,608 B
  float*          wofft = (float*)(ws);
  unsigned short* wtbs  = (unsigned short*)(ws + 41472);
  float*          offs  = (float*)(ws + 115200);
  unsigned short* xt    = (unsigned short*)(ws + 4833792);

  hipLaunchKernelGGL(k_prep, dim3(144),  dim3(256), 0, stream, w, w_off, wofft, wtbs);
  hipLaunchKernelGGL(k_tr,   dim3(512),  dim3(256), 0, stream, x, (unsigned int*)xt);
  hipLaunchKernelGGL(k_off,  dim3(2048), dim3(256), 0, stream, xt, wofft, b_off, offs);
  hipLaunchKernelGGL(k_fuse, dim3(1024), dim3(256), 0, stream, xt, offs, wtbs, bias, out);
}

// Round 7
// 54.583 us; speedup vs baseline: 11.1708x; 1.4573x over previous
//
#include <hip/hip_runtime.h>
#include <hip/hip_bf16.h>

#define HW 128
#define PW 130   // padded width/height

typedef float f32x4 __attribute__((ext_vector_type(4)));
typedef short bf16x8 __attribute__((ext_vector_type(8)));

__device__ __forceinline__ unsigned short f2bf(float v) {
  __hip_bfloat16 h = __float2bfloat16(v);
  return *reinterpret_cast<unsigned short*>(&h);
}

__device__ __forceinline__ void bf8_to_f32(const int4& r, float* f) {
  const unsigned int* u = reinterpret_cast<const unsigned int*>(&r);
#pragma unroll
  for (int k = 0; k < 4; ++k) {
    f[2 * k]     = __uint_as_float(u[k] << 16);
    f[2 * k + 1] = __uint_as_float(u[k] & 0xffff0000u);
  }
}

__device__ __forceinline__ void gld_lds16(const void* g, void* l) {
  __builtin_amdgcn_global_load_lds(
      (const __attribute__((address_space(1))) void*)g,
      (__attribute__((address_space(3))) void*)l, 16, 0, 0);
}

// ---------------- k_prep ----------------
// wtbs[(t*64+o)*64 + ((c8^(o&7))*8)+cj] = bf16(w[o][c][t])   (main-GEMM B, chunk-swizzled)
// wb: offsets-conv B in MFMA fragment order:
//   frag f = t*4 + kk*2 + n; elem i = f*512 + lane*8 + j
//   wb[i] = bf16(w_off[o=n*16+(lane&15)][c=kk*32+(lane>>4)*8+j][t]), 0 if o>=18
__global__ __launch_bounds__(256) void k_prep(const float* __restrict__ w,
                                              const float* __restrict__ w_off,
                                              unsigned short* __restrict__ wtbs,
                                              unsigned short* __restrict__ wb) {
  int i = blockIdx.x * 256 + threadIdx.x;
  if (i < 36864) {
    int o = i & 63, tc = i >> 6;
    int c = tc & 63, t = tc >> 6;
    float v = w[o * 576 + c * 9 + t];
    int c8 = c >> 3, cj = c & 7;
    wtbs[(t * 64 + o) * 64 + (((c8 ^ (o & 7)) << 3) + cj)] = f2bf(v);
  }
  if (i < 18432) {
    int j = i & 7, lane = (i >> 3) & 63, f = i >> 9;
    int n = f & 1, kk = (f >> 1) & 1, t = f >> 2;
    int o = n * 16 + (lane & 15);
    int c = kk * 32 + (lane >> 4) * 8 + j;
    float v = (o < 18) ? w_off[o * 576 + c * 9 + t] : 0.0f;
    wb[i] = f2bf(v);
  }
}

// ---------------- k_tr: x NCHW f32 -> xt[b][1+h][1+w][c] bf16 (zero border via memset) ----
__global__ __launch_bounds__(256) void k_tr(const float* __restrict__ x,
                                            unsigned int* __restrict__ xt_u32) {
  __shared__ float tile[64 * 129];
  int blk = blockIdx.x;                   // b*128 + h
  int h = blk & 127, b = blk >> 7;
  int tid = threadIdx.x;
  int w0 = tid & 127, ch = tid >> 7;
  const float* xb = x + ((size_t)b * 64 * HW + h) * HW;
#pragma unroll
  for (int k = 0; k < 32; ++k) {
    int c = ch * 32 + k;
    tile[c * 129 + (w0 ^ (c & 1))] = xb[c * (HW * HW) + w0];
  }
  __syncthreads();
  int c2 = tid & 31, wg = tid >> 5;
#pragma unroll
  for (int k = 0; k < 16; ++k) {
    int ww = wg * 16 + k;
    float lo = tile[(2 * c2) * 129 + ww];
    float hi = tile[(2 * c2 + 1) * 129 + (ww ^ 1)];
    xt_u32[((size_t)(b * PW + h + 1) * PW + (ww + 1)) * 32 + c2] =
        (unsigned int)f2bf(lo) | ((unsigned int)f2bf(hi) << 16);
  }
}

// ---------------- k_offm: offsets conv as MFMA GEMM ----------------
// Block = 64 pixels (half row). Stage 3x66x64 bf16 slab once (swizzled via
// pre-swizzled global source); 9 taps read shifted rows; B frags prefetched
// from wb per tap. M=64, K=576, N=32 (18 used).
__global__ __launch_bounds__(256) void k_offm(const unsigned short* __restrict__ xt,
                                              const unsigned short* __restrict__ wb,
                                              const float* __restrict__ b_off,
                                              float* __restrict__ offs) {
  __shared__ __align__(16) unsigned short slabA[12672];   // 3*66*64
  int bid = blockIdx.x;
  bid = (bid & 7) * 128 + (bid >> 3);     // XCD swizzle (1024 % 8 == 0)
  int pix0 = bid * 64;
  int h = (pix0 >> 7) & 127, b = pix0 >> 14, wbase = pix0 & 127;
  int tid = threadIdx.x, wid = tid >> 6, lane = tid & 63;
  int l15 = lane & 15, l4 = lane >> 4;

  const unsigned short* xb = xt + (size_t)b * (PW * PW * 64);
  // stage A slab: storage row S = r*66+u covers (yp=h+r, xp=wbase+u); chunk-XOR by S&7
  for (int i = wid; i < 25; i += 4) {
    int e = i * 512 + lane * 8;
    if (e < 12672) {
      int S = e >> 6, c8 = (e >> 3) & 7;
      int r = S / 66, u = S - r * 66;
      gld_lds16(xb + ((size_t)((h + r) * PW + wbase + u)) * 64 + ((c8 ^ (S & 7)) << 3),
                &slabA[i * 512]);
    }
  }

  const int4* wb4 = reinterpret_cast<const int4*>(wb);
  int4 bc[4], bn[4];
#pragma unroll
  for (int q = 0; q < 4; ++q) bc[q] = wb4[q * 64 + lane];   // tap 0 frags
  asm volatile("s_waitcnt vmcnt(0)" ::: "memory");
  __builtin_amdgcn_s_barrier();

  f32x4 acc0 = {0.f, 0.f, 0.f, 0.f}, acc1 = {0.f, 0.f, 0.f, 0.f};
#pragma unroll 1
  for (int t = 0; t < 9; ++t) {
    if (t < 8) {
#pragma unroll
      for (int q = 0; q < 4; ++q) bn[q] = wb4[((t + 1) * 4 + q) * 64 + lane];
    }
    int ti = t / 3, tj = t - ti * 3;
    int S = ti * 66 + wid * 16 + l15 + tj;
#pragma unroll
    for (int kk = 0; kk < 2; ++kk) {
      int phys = (kk * 4 + l4) ^ (S & 7);
      bf16x8 a = *reinterpret_cast<const bf16x8*>(
          reinterpret_cast<const char*>(slabA) + S * 128 + phys * 16);
      acc0 = __builtin_amdgcn_mfma_f32_16x16x32_bf16(a, *(const bf16x8*)&bc[kk * 2 + 0], acc0, 0, 0, 0);
      acc1 = __builtin_amdgcn_mfma_f32_16x16x32_bf16(a, *(const bf16x8*)&bc[kk * 2 + 1], acc1, 0, 0, 0);
    }
#pragma unroll
    for (int q = 0; q < 4; ++q) bc[q] = bn[q];
  }

  // D: col=lane&15 -> o, row=(lane>>4)*4+reg -> pixel
  float bo0 = b_off[l15];
  int pixr = pix0 + wid * 16 + l4 * 4;
#pragma unroll
  for (int reg = 0; reg < 4; ++reg)
    offs[(size_t)(pixr + reg) * 18 + l15] = acc0[reg] + bo0;
  if (l15 < 2) {
    float bo1 = b_off[16 + l15];
#pragma unroll
    for (int reg = 0; reg < 4; ++reg)
      offs[(size_t)(pixr + reg) * 18 + 16 + l15] = acc1[reg] + bo1;
  }
}

// ---------------- k_fuse: gather + MFMA GEMM (padded xt addressing) ----------------
__global__ __launch_bounds__(256) void k_fuse(const unsigned short* __restrict__ xt,
                                              const float* __restrict__ offs,
                                              const unsigned short* __restrict__ wtbs,
                                              const float* __restrict__ bias,
                                              float* __restrict__ out) {
  __shared__ __align__(16) unsigned short ldsA[2][4096];
  __shared__ __align__(16) unsigned short ldsB[2][4096];
  __shared__ __align__(16) float loff[64 * 18];

  int bid = blockIdx.x;
  bid = (bid & 7) * 128 + (bid >> 3);     // XCD swizzle (1024 % 8 == 0)
  int pix0 = bid * 64;
  int h = (pix0 >> 7) & 127, b = pix0 >> 14, wbase = pix0 & 127;

  int tid = threadIdx.x;
  int wid = tid >> 6, lane = tid & 63;
  int l15 = lane & 15, l4 = lane >> 4;
  int wm = wid >> 1, wn = wid & 1;
  int g = tid & 7, p2 = tid >> 3;

  for (int i = tid; i < 288; i += 256)
    reinterpret_cast<float4*>(loff)[i] =
        reinterpret_cast<const float4*>(offs + (size_t)pix0 * 18)[i];

  const unsigned short* xtb = xt + (size_t)b * (PW * PW * 64) + g * 8;

  auto stageB = [&](int t, int bsel) {
#pragma unroll
    for (int j = 0; j < 2; ++j) {
      int instr = j * 4 + wid;
      int cg = instr * 64 + lane;
      int row = cg >> 3, c8 = cg & 7;
      gld_lds16(wtbs + ((size_t)(t * 64 + row) * 64 + c8 * 8),
                &ldsB[bsel][instr * 512]);
    }
  };

  int4 r[2][4];
  float fw[2][4];

  auto issue_gather = [&](int t) {
    int ti = t / 3, tj = t % 3;
#pragma unroll
    for (int k = 0; k < 2; ++k) {
      int pp = p2 + 32 * k;
      float2 d = *reinterpret_cast<const float2*>(&loff[pp * 18 + 2 * t]);
      float py = (float)(h + ti - 1) + d.x;
      float px = (float)(wbase + pp + tj - 1) + d.y;
      float y0f = floorf(py), x0f = floorf(px);
      float wy = py - y0f, wxf = px - x0f;
      int y0 = (int)y0f, x0 = (int)x0f;
      int y1 = y0 + 1, x1 = x0 + 1;
      fw[k][0] = (((unsigned)y0 < HW) && ((unsigned)x0 < HW)) ? (1.f - wy) * (1.f - wxf) : 0.f;
      fw[k][1] = (((unsigned)y0 < HW) && ((unsigned)x1 < HW)) ? (1.f - wy) * wxf : 0.f;
      fw[k][2] = (((unsigned)y1 < HW) && ((unsigned)x0 < HW)) ? wy * (1.f - wxf) : 0.f;
      fw[k][3] = (((unsigned)y1 < HW) && ((unsigned)x1 < HW)) ? wy * wxf : 0.f;
      int y0c = min(max(y0, 0), HW - 1) + 1, y1c = min(max(y1, 0), HW - 1) + 1;
      int x0c = min(max(x0, 0), HW - 1) + 1, x1c = min(max(x1, 0), HW - 1) + 1;
      r[k][0] = *reinterpret_cast<const int4*>(xtb + ((size_t)y0c * PW + x0c) * 64);
      r[k][1] = *reinterpret_cast<const int4*>(xtb + ((size_t)y0c * PW + x1c) * 64);
      r[k][2] = *reinterpret_cast<const int4*>(xtb + ((size_t)y1c * PW + x0c) * 64);
      r[k][3] = *reinterpret_cast<const int4*>(xtb + ((size_t)y1c * PW + x1c) * 64);
    }
  };

  auto lerp_write = [&](int bsel) {
#pragma unroll
    for (int k = 0; k < 2; ++k) {
      int pp = p2 + 32 * k;
      float v00[8], v01[8], v10[8], v11[8];
      bf8_to_f32(r[k][0], v00); bf8_to_f32(r[k][1], v01);
      bf8_to_f32(r[k][2], v10); bf8_to_f32(r[k][3], v11);
      unsigned int pk[4];
#pragma unroll
      for (int j = 0; j < 4; ++j) {
        float slo = fmaf(v11[2 * j], fw[k][3],
                    fmaf(v10[2 * j], fw[k][2],
                    fmaf(v01[2 * j], fw[k][1], v00[2 * j] * fw[k][0])));
        float shi = fmaf(v11[2 * j + 1], fw[k][3],
                    fmaf(v10[2 * j + 1], fw[k][2],
                    fmaf(v01[2 * j + 1], fw[k][1], v00[2 * j + 1] * fw[k][0])));
        pk[j] = (unsigned int)f2bf(slo) | ((unsigned int)f2bf(shi) << 16);
      }
      *reinterpret_cast<int4*>(&ldsA[bsel][pp * 64 + ((g ^ (pp & 7)) << 3)]) =
          *reinterpret_cast<int4*>(pk);
    }
  };

  f32x4 acc00 = {0.f, 0.f, 0.f, 0.f}, acc01 = {0.f, 0.f, 0.f, 0.f};
  f32x4 acc10 = {0.f, 0.f, 0.f, 0.f}, acc11 = {0.f, 0.f, 0.f, 0.f};

  __syncthreads();                 // loff ready
  stageB(0, 0);
  issue_gather(0);
  lerp_write(0);
  asm volatile("s_waitcnt vmcnt(0)" ::: "memory");
  __syncthreads();                 // A0, B0 ready

#pragma unroll 1
  for (int t = 0; t < 9; ++t) {
    int cur = t & 1;
    if (t < 8) {
      stageB(t + 1, cur ^ 1);
      issue_gather(t + 1);
    }
    const char* Ab = (const char*)ldsA[cur];
    const char* Bb = (const char*)ldsB[cur];
#pragma unroll
    for (int kk = 0; kk < 2; ++kk) {
      int sw = (((kk * 4 + l4) ^ (l15 & 7)) << 4) + l15 * 128;
      bf16x8 a0 = *(const bf16x8*)(Ab + (wm * 32 + 0)  * 128 + sw);
      bf16x8 a1 = *(const bf16x8*)(Ab + (wm * 32 + 16) * 128 + sw);
      bf16x8 b0 = *(const bf16x8*)(Bb + (wn * 32 + 0)  * 128 + sw);
      bf16x8 b1 = *(const bf16x8*)(Bb + (wn * 32 + 16) * 128 + sw);
      acc00 = __builtin_amdgcn_mfma_f32_16x16x32_bf16(a0, b0, acc00, 0, 0, 0);
      acc01 = __builtin_amdgcn_mfma_f32_16x16x32_bf16(a0, b1, acc01, 0, 0, 0);
      acc10 = __builtin_amdgcn_mfma_f32_16x16x32_bf16(a1, b0, acc10, 0, 0, 0);
      acc11 = __builtin_amdgcn_mfma_f32_16x16x32_bf16(a1, b1, acc11, 0, 0, 0);
    }
    if (t < 8) lerp_write(cur ^ 1);
    asm volatile("s_waitcnt vmcnt(0)" ::: "memory");
    __syncthreads();
  }

  int m0 = wm * 32 + (l4 << 2);
#pragma unroll
  for (int fm = 0; fm < 2; ++fm) {
#pragma unroll
    for (int fn = 0; fn < 2; ++fn) {
      f32x4 a = (fm == 0) ? ((fn == 0) ? acc00 : acc01) : ((fn == 0) ? acc10 : acc11);
      int o = wn * 32 + fn * 16 + l15;
      int pix = pix0 + m0 + fm * 16;
      int bb = pix >> 14, hw = pix & 16383;
      float bz = bias[o];
      float4 st = make_float4(a[0] + bz, a[1] + bz, a[2] + bz, a[3] + bz);
      *reinterpret_cast<float4*>(&out[(((size_t)bb * 64 + o) << 14) + hw]) = st;
    }
  }
}

extern "C" void kernel_launch(void* const* d_in, const int* in_sizes, int n_in,
                              void* d_out, int out_size, void* d_ws, size_t ws_size,
                              hipStream_t stream) {
  const float* x     = (const float*)d_in[0];
  const float* w_off = (const float*)d_in[1];
  const float* b_off = (const float*)d_in[2];
  const float* w     = (const float*)d_in[3];
  const float* bias  = (const float*)d_in[4];
  float* out = (float*)d_out;
  char* ws   = (char*)d_ws;

  // ws layout (BYTES):
  //   wtbs [0,         73,728)      36,864 bf16 (main-GEMM B, swizzled)
  //   wb   [73,728,    110,592)     18,432 bf16 (offsets-conv B frags)
  //   offs [110,592,   4,829,184)   65,536*18 f32
  //   xt   [4,829,184, 13,481,984)  4*130*130*64 bf16 (padded, zero border)
  unsigned short* wtbs = (unsigned short*)(ws);
  unsigned short* wb   = (unsigned short*)(ws + 73728);
  float*          offs = (float*)(ws + 110592);
  unsigned short* xt   = (unsigned short*)(ws + 4829184);

  hipLaunchKernelGGL(k_prep, dim3(144), dim3(256), 0, stream, w, w_off, wtbs, wb);
  hipMemsetAsync(xt, 0, 8652800, stream);
  hipLaunchKernelGGL(k_tr,   dim3(512),  dim3(256), 0, stream, x, (unsigned int*)xt);
  hipLaunchKernelGGL(k_offm, dim3(1024), dim3(256), 0, stream, xt, wb, b_off, offs);
  hipLaunchKernelGGL(k_fuse, dim3(1024), dim3(256), 0, stream, xt, offs, wtbs, bias, out);
}

// Round 8
// 51.432 us; speedup vs baseline: 11.8551x; 1.0613x over previous
//
#include <hip/hip_runtime.h>
#include <hip/hip_bf16.h>

#define HW 128
#define PW 130   // padded width/height

typedef float f32x4 __attribute__((ext_vector_type(4)));
typedef short bf16x8 __attribute__((ext_vector_type(8)));

__device__ __forceinline__ unsigned short f2bf(float v) {
  __hip_bfloat16 h = __float2bfloat16(v);
  return *reinterpret_cast<unsigned short*>(&h);
}

__device__ __forceinline__ void bf8_to_f32(const int4& r, float* f) {
  const unsigned int* u = reinterpret_cast<const unsigned int*>(&r);
#pragma unroll
  for (int k = 0; k < 4; ++k) {
    f[2 * k]     = __uint_as_float(u[k] << 16);
    f[2 * k + 1] = __uint_as_float(u[k] & 0xffff0000u);
  }
}

__device__ __forceinline__ void gld_lds16(const void* g, void* l) {
  __builtin_amdgcn_global_load_lds(
      (const __attribute__((address_space(1))) void*)g,
      (__attribute__((address_space(3))) void*)l, 16, 0, 0);
}

// ---------------- k_prep ----------------
// wtbs[(t*64+o)*64 + ((c8^(o&7))*8)+cj] = bf16(w[o][c][t])   (main-GEMM B, chunk-swizzled)
// wb: offsets-conv B in MFMA fragment order:
//   frag f = t*4 + kk*2 + n; elem i = f*512 + lane*8 + j
//   wb[i] = bf16(w_off[o=n*16+(lane&15)][c=kk*32+(lane>>4)*8+j][t]), 0 if o>=18
__global__ __launch_bounds__(256) void k_prep(const float* __restrict__ w,
                                              const float* __restrict__ w_off,
                                              unsigned short* __restrict__ wtbs,
                                              unsigned short* __restrict__ wb) {
  int i = blockIdx.x * 256 + threadIdx.x;
  if (i < 36864) {
    int o = i & 63, tc = i >> 6;
    int c = tc & 63, t = tc >> 6;
    float v = w[o * 576 + c * 9 + t];
    int c8 = c >> 3, cj = c & 7;
    wtbs[(t * 64 + o) * 64 + (((c8 ^ (o & 7)) << 3) + cj)] = f2bf(v);
  }
  if (i < 18432) {
    int j = i & 7, lane = (i >> 3) & 63, f = i >> 9;
    int n = f & 1, kk = (f >> 1) & 1, t = f >> 2;
    int o = n * 16 + (lane & 15);
    int c = kk * 32 + (lane >> 4) * 8 + j;
    float v = (o < 18) ? w_off[o * 576 + c * 9 + t] : 0.0f;
    wb[i] = f2bf(v);
  }
}

// ---------------- k_zb: zero ONLY the 1-px pad border of xt ----------------
// (r7: hipMemsetAsync of the full 8.65MB buffer ran at 200 GB/s = 43us, 80% of total.
//  Interior is rewritten by k_tr every call; border = 4*516 cells * 64ch = 264KB.)
__global__ __launch_bounds__(256) void k_zb(unsigned int* __restrict__ xt_u32) {
  int idx = blockIdx.x * 256 + threadIdx.x;   // 2064 cells * 32 u32 = 66048
  if (idx >= 66048) return;
  int c2 = idx & 31;
  int ci = idx >> 5;                          // 0..2063
  int b = ci / 516, cell = ci - b * 516;
  int row, col;
  if (cell < 130)      { row = 0;   col = cell; }
  else if (cell < 260) { row = 129; col = cell - 130; }
  else { int k = cell - 260; row = 1 + (k >> 1); col = (k & 1) ? 129 : 0; }
  xt_u32[((size_t)(b * PW + row) * PW + col) * 32 + c2] = 0u;
}

// ---------------- k_tr: x NCHW f32 -> xt[b][1+h][1+w][c] bf16 ----------------
__global__ __launch_bounds__(256) void k_tr(const float* __restrict__ x,
                                            unsigned int* __restrict__ xt_u32) {
  __shared__ float tile[64 * 129];
  int blk = blockIdx.x;                   // b*128 + h
  int h = blk & 127, b = blk >> 7;
  int tid = threadIdx.x;
  int w0 = tid & 127, ch = tid >> 7;
  const float* xb = x + ((size_t)b * 64 * HW + h) * HW;
#pragma unroll
  for (int k = 0; k < 32; ++k) {
    int c = ch * 32 + k;
    tile[c * 129 + (w0 ^ (c & 1))] = xb[c * (HW * HW) + w0];
  }
  __syncthreads();
  int c2 = tid & 31, wg = tid >> 5;
#pragma unroll
  for (int k = 0; k < 16; ++k) {
    int ww = wg * 16 + k;
    float lo = tile[(2 * c2) * 129 + ww];
    float hi = tile[(2 * c2 + 1) * 129 + (ww ^ 1)];
    xt_u32[((size_t)(b * PW + h + 1) * PW + (ww + 1)) * 32 + c2] =
        (unsigned int)f2bf(lo) | ((unsigned int)f2bf(hi) << 16);
  }
}

// ---------------- k_offm: offsets conv as MFMA GEMM ----------------
__global__ __launch_bounds__(256) void k_offm(const unsigned short* __restrict__ xt,
                                              const unsigned short* __restrict__ wb,
                                              const float* __restrict__ b_off,
                                              float* __restrict__ offs) {
  __shared__ __align__(16) unsigned short slabA[12672];   // 3*66*64
  int bid = blockIdx.x;
  bid = (bid & 7) * 128 + (bid >> 3);     // XCD swizzle (1024 % 8 == 0)
  int pix0 = bid * 64;
  int h = (pix0 >> 7) & 127, b = pix0 >> 14, wbase = pix0 & 127;
  int tid = threadIdx.x, wid = tid >> 6, lane = tid & 63;
  int l15 = lane & 15, l4 = lane >> 4;

  const unsigned short* xb = xt + (size_t)b * (PW * PW * 64);
  // stage A slab: storage row S = r*66+u covers (yp=h+r, xp=wbase+u); chunk-XOR by S&7
  for (int i = wid; i < 25; i += 4) {
    int e = i * 512 + lane * 8;
    if (e < 12672) {
      int S = e >> 6, c8 = (e >> 3) & 7;
      int r = S / 66, u = S - r * 66;
      gld_lds16(xb + ((size_t)((h + r) * PW + wbase + u)) * 64 + ((c8 ^ (S & 7)) << 3),
                &slabA[i * 512]);
    }
  }

  const int4* wb4 = reinterpret_cast<const int4*>(wb);
  int4 bc[4], bn[4];
#pragma unroll
  for (int q = 0; q < 4; ++q) bc[q] = wb4[q * 64 + lane];   // tap 0 frags
  asm volatile("s_waitcnt vmcnt(0)" ::: "memory");
  __builtin_amdgcn_s_barrier();

  f32x4 acc0 = {0.f, 0.f, 0.f, 0.f}, acc1 = {0.f, 0.f, 0.f, 0.f};
#pragma unroll 1
  for (int t = 0; t < 9; ++t) {
    if (t < 8) {
#pragma unroll
      for (int q = 0; q < 4; ++q) bn[q] = wb4[((t + 1) * 4 + q) * 64 + lane];
    }
    int ti = t / 3, tj = t - ti * 3;
    int S = ti * 66 + wid * 16 + l15 + tj;
#pragma unroll
    for (int kk = 0; kk < 2; ++kk) {
      int phys = (kk * 4 + l4) ^ (S & 7);
      bf16x8 a = *reinterpret_cast<const bf16x8*>(
          reinterpret_cast<const char*>(slabA) + S * 128 + phys * 16);
      acc0 = __builtin_amdgcn_mfma_f32_16x16x32_bf16(a, *(const bf16x8*)&bc[kk * 2 + 0], acc0, 0, 0, 0);
      acc1 = __builtin_amdgcn_mfma_f32_16x16x32_bf16(a, *(const bf16x8*)&bc[kk * 2 + 1], acc1, 0, 0, 0);
    }
#pragma unroll
    for (int q = 0; q < 4; ++q) bc[q] = bn[q];
  }

  // D: col=lane&15 -> o, row=(lane>>4)*4+reg -> pixel
  float bo0 = b_off[l15];
  int pixr = pix0 + wid * 16 + l4 * 4;
#pragma unroll
  for (int reg = 0; reg < 4; ++reg)
    offs[(size_t)(pixr + reg) * 18 + l15] = acc0[reg] + bo0;
  if (l15 < 2) {
    float bo1 = b_off[16 + l15];
#pragma unroll
    for (int reg = 0; reg < 4; ++reg)
      offs[(size_t)(pixr + reg) * 18 + 16 + l15] = acc1[reg] + bo1;
  }
}

// ---------------- k_fuse: gather + MFMA GEMM (padded xt addressing) ----------------
__global__ __launch_bounds__(256) void k_fuse(const unsigned short* __restrict__ xt,
                                              const float* __restrict__ offs,
                                              const unsigned short* __restrict__ wtbs,
                                              const float* __restrict__ bias,
                                              float* __restrict__ out) {
  __shared__ __align__(16) unsigned short ldsA[2][4096];
  __shared__ __align__(16) unsigned short ldsB[2][4096];
  __shared__ __align__(16) float loff[64 * 18];

  int bid = blockIdx.x;
  bid = (bid & 7) * 128 + (bid >> 3);     // XCD swizzle (1024 % 8 == 0)
  int pix0 = bid * 64;
  int h = (pix0 >> 7) & 127, b = pix0 >> 14, wbase = pix0 & 127;

  int tid = threadIdx.x;
  int wid = tid >> 6, lane = tid & 63;
  int l15 = lane & 15, l4 = lane >> 4;
  int wm = wid >> 1, wn = wid & 1;
  int g = tid & 7, p2 = tid >> 3;

  for (int i = tid; i < 288; i += 256)
    reinterpret_cast<float4*>(loff)[i] =
        reinterpret_cast<const float4*>(offs + (size_t)pix0 * 18)[i];

  const unsigned short* xtb = xt + (size_t)b * (PW * PW * 64) + g * 8;

  auto stageB = [&](int t, int bsel) {
#pragma unroll
    for (int j = 0; j < 2; ++j) {
      int instr = j * 4 + wid;
      int cg = instr * 64 + lane;
      int row = cg >> 3, c8 = cg & 7;
      gld_lds16(wtbs + ((size_t)(t * 64 + row) * 64 + c8 * 8),
                &ldsB[bsel][instr * 512]);
    }
  };

  int4 r[2][4];
  float fw[2][4];

  auto issue_gather = [&](int t) {
    int ti = t / 3, tj = t % 3;
#pragma unroll
    for (int k = 0; k < 2; ++k) {
      int pp = p2 + 32 * k;
      float2 d = *reinterpret_cast<const float2*>(&loff[pp * 18 + 2 * t]);
      float py = (float)(h + ti - 1) + d.x;
      float px = (float)(wbase + pp + tj - 1) + d.y;
      float y0f = floorf(py), x0f = floorf(px);
      float wy = py - y0f, wxf = px - x0f;
      int y0 = (int)y0f, x0 = (int)x0f;
      int y1 = y0 + 1, x1 = x0 + 1;
      fw[k][0] = (((unsigned)y0 < HW) && ((unsigned)x0 < HW)) ? (1.f - wy) * (1.f - wxf) : 0.f;
      fw[k][1] = (((unsigned)y0 < HW) && ((unsigned)x1 < HW)) ? (1.f - wy) * wxf : 0.f;
      fw[k][2] = (((unsigned)y1 < HW) && ((unsigned)x0 < HW)) ? wy * (1.f - wxf) : 0.f;
      fw[k][3] = (((unsigned)y1 < HW) && ((unsigned)x1 < HW)) ? wy * wxf : 0.f;
      int y0c = min(max(y0, 0), HW - 1) + 1, y1c = min(max(y1, 0), HW - 1) + 1;
      int x0c = min(max(x0, 0), HW - 1) + 1, x1c = min(max(x1, 0), HW - 1) + 1;
      r[k][0] = *reinterpret_cast<const int4*>(xtb + ((size_t)y0c * PW + x0c) * 64);
      r[k][1] = *reinterpret_cast<const int4*>(xtb + ((size_t)y0c * PW + x1c) * 64);
      r[k][2] = *reinterpret_cast<const int4*>(xtb + ((size_t)y1c * PW + x0c) * 64);
      r[k][3] = *reinterpret_cast<const int4*>(xtb + ((size_t)y1c * PW + x1c) * 64);
    }
  };

  auto lerp_write = [&](int bsel) {
#pragma unroll
    for (int k = 0; k < 2; ++k) {
      int pp = p2 + 32 * k;
      float v00[8], v01[8], v10[8], v11[8];
      bf8_to_f32(r[k][0], v00); bf8_to_f32(r[k][1], v01);
      bf8_to_f32(r[k][2], v10); bf8_to_f32(r[k][3], v11);
      unsigned int pk[4];
#pragma unroll
      for (int j = 0; j < 4; ++j) {
        float slo = fmaf(v11[2 * j], fw[k][3],
                    fmaf(v10[2 * j], fw[k][2],
                    fmaf(v01[2 * j], fw[k][1], v00[2 * j] * fw[k][0])));
        float shi = fmaf(v11[2 * j + 1], fw[k][3],
                    fmaf(v10[2 * j + 1], fw[k][2],
                    fmaf(v01[2 * j + 1], fw[k][1], v00[2 * j + 1] * fw[k][0])));
        pk[j] = (unsigned int)f2bf(slo) | ((unsigned int)f2bf(shi) << 16);
      }
      *reinterpret_cast<int4*>(&ldsA[bsel][pp * 64 + ((g ^ (pp & 7)) << 3)]) =
          *reinterpret_cast<int4*>(pk);
    }
  };

  f32x4 acc00 = {0.f, 0.f, 0.f, 0.f}, acc01 = {0.f, 0.f, 0.f, 0.f};
  f32x4 acc10 = {0.f, 0.f, 0.f, 0.f}, acc11 = {0.f, 0.f, 0.f, 0.f};

  __syncthreads();                 // loff ready
  stageB(0, 0);
  issue_gather(0);
  lerp_write(0);
  asm volatile("s_waitcnt vmcnt(0)" ::: "memory");
  __syncthreads();                 // A0, B0 ready

#pragma unroll 1
  for (int t = 0; t < 9; ++t) {
    int cur = t & 1;
    if (t < 8) {
      stageB(t + 1, cur ^ 1);
      issue_gather(t + 1);
    }
    const char* Ab = (const char*)ldsA[cur];
    const char* Bb = (const char*)ldsB[cur];
#pragma unroll
    for (int kk = 0; kk < 2; ++kk) {
      int sw = (((kk * 4 + l4) ^ (l15 & 7)) << 4) + l15 * 128;
      bf16x8 a0 = *(const bf16x8*)(Ab + (wm * 32 + 0)  * 128 + sw);
      bf16x8 a1 = *(const bf16x8*)(Ab + (wm * 32 + 16) * 128 + sw);
      bf16x8 b0 = *(const bf16x8*)(Bb + (wn * 32 + 0)  * 128 + sw);
      bf16x8 b1 = *(const bf16x8*)(Bb + (wn * 32 + 16) * 128 + sw);
      acc00 = __builtin_amdgcn_mfma_f32_16x16x32_bf16(a0, b0, acc00, 0, 0, 0);
      acc01 = __builtin_amdgcn_mfma_f32_16x16x32_bf16(a0, b1, acc01, 0, 0, 0);
      acc10 = __builtin_amdgcn_mfma_f32_16x16x32_bf16(a1, b0, acc10, 0, 0, 0);
      acc11 = __builtin_amdgcn_mfma_f32_16x16x32_bf16(a1, b1, acc11, 0, 0, 0);
    }
    if (t < 8) lerp_write(cur ^ 1);
    asm volatile("s_waitcnt vmcnt(0)" ::: "memory");
    __syncthreads();
  }

  int m0 = wm * 32 + (l4 << 2);
#pragma unroll
  for (int fm = 0; fm < 2; ++fm) {
#pragma unroll
    for (int fn = 0; fn < 2; ++fn) {
      f32x4 a = (fm == 0) ? ((fn == 0) ? acc00 : acc01) : ((fn == 0) ? acc10 : acc11);
      int o = wn * 32 + fn * 16 + l15;
      int pix = pix0 + m0 + fm * 16;
      int bb = pix >> 14, hw = pix & 16383;
      float bz = bias[o];
      float4 st = make_float4(a[0] + bz, a[1] + bz, a[2] + bz, a[3] + bz);
      *reinterpret_cast<float4*>(&out[(((size_t)bb * 64 + o) << 14) + hw]) = st;
    }
  }
}

extern "C" void kernel_launch(void* const* d_in, const int* in_sizes, int n_in,
                              void* d_out, int out_size, void* d_ws, size_t ws_size,
                              hipStream_t stream) {
  const float* x     = (const float*)d_in[0];
  const float* w_off = (const float*)d_in[1];
  const float* b_off = (const float*)d_in[2];
  const float* w     = (const float*)d_in[3];
  const float* bias  = (const float*)d_in[4];
  float* out = (float*)d_out;
  char* ws   = (char*)d_ws;

  // ws layout (BYTES):
  //   wtbs [0,         73,728)      36,864 bf16 (main-GEMM B, swizzled)
  //   wb   [73,728,    110,592)     18,432 bf16 (offsets-conv B frags)
  //   offs [110,592,   4,829,184)   65,536*18 f32
  //   xt   [4,829,184, 13,481,984)  4*130*130*64 bf16 (padded, zero border)
  unsigned short* wtbs = (unsigned short*)(ws);
  unsigned short* wb   = (unsigned short*)(ws + 73728);
  float*          offs = (float*)(ws + 110592);
  unsigned short* xt   = (unsigned short*)(ws + 4829184);

  hipLaunchKernelGGL(k_prep, dim3(144), dim3(256), 0, stream, w, w_off, wtbs, wb);
  hipLaunchKernelGGL(k_zb,   dim3(258), dim3(256), 0, stream, (unsigned int*)xt);
  hipLaunchKernelGGL(k_tr,   dim3(512),  dim3(256), 0, stream, x, (unsigned int*)xt);
  hipLaunchKernelGGL(k_offm, dim3(1024), dim3(256), 0, stream, xt, wb, b_off, offs);
  hipLaunchKernelGGL(k_fuse, dim3(1024), dim3(256), 0, stream, xt, offs, wtbs, bias, out);
}

// Round 9
// 41.156 us; speedup vs baseline: 14.8151x; 1.2497x over previous
//
#include <hip/hip_runtime.h>
#include <hip/hip_bf16.h>

#define HW 128
#define PW 130   // padded width/height

typedef float f32x4 __attribute__((ext_vector_type(4)));
typedef short bf16x8 __attribute__((ext_vector_type(8)));

__device__ __forceinline__ unsigned short f2bf(float v) {
  __hip_bfloat16 h = __float2bfloat16(v);
  return *reinterpret_cast<unsigned short*>(&h);
}

__device__ __forceinline__ void bf8_to_f32(const int4& r, float* f) {
  const unsigned int* u = reinterpret_cast<const unsigned int*>(&r);
#pragma unroll
  for (int k = 0; k < 4; ++k) {
    f[2 * k]     = __uint_as_float(u[k] << 16);
    f[2 * k + 1] = __uint_as_float(u[k] & 0xffff0000u);
  }
}

__device__ __forceinline__ void gld_lds16(const void* g, void* l) {
  __builtin_amdgcn_global_load_lds(
      (const __attribute__((address_space(1))) void*)g,
      (__attribute__((address_space(3))) void*)l, 16, 0, 0);
}

// ---------------- k_tr: prep + border-zero + NCHW->padded-NHWC transpose ----------------
// blocks <144 also build wtbs (main-GEMM B, chunk-swizzled) and wb (offsets-B MFMA frags);
// first 16512 global threads also zero the 1-px pad border (int4 stores).
__global__ __launch_bounds__(256) void k_tr(const float* __restrict__ x,
                                            unsigned int* __restrict__ xt_u32,
                                            const float* __restrict__ w,
                                            const float* __restrict__ w_off,
                                            unsigned short* __restrict__ wtbs,
                                            unsigned short* __restrict__ wb) {
  __shared__ float tile[64 * 129];
  int blk = blockIdx.x;                   // b*128 + h
  int tid = threadIdx.x;
  int gi = blk * 256 + tid;

  // ---- folded k_prep ----
  if (blk < 144) {
    if (gi < 36864) {
      int o = gi & 63, tc = gi >> 6;
      int c = tc & 63, t = tc >> 6;
      float v = w[o * 576 + c * 9 + t];
      int c8 = c >> 3, cj = c & 7;
      wtbs[(t * 64 + o) * 64 + (((c8 ^ (o & 7)) << 3) + cj)] = f2bf(v);
    }
    if (gi < 18432) {
      int j = gi & 7, lane = (gi >> 3) & 63, f = gi >> 9;
      int n = f & 1, kk = (f >> 1) & 1, t = f >> 2;
      int o = n * 16 + (lane & 15);
      int c = kk * 32 + (lane >> 4) * 8 + j;
      float v = (o < 18) ? w_off[o * 576 + c * 9 + t] : 0.0f;
      wb[gi] = f2bf(v);
    }
  }
  // ---- folded border zero: 2064 cells * 8 int4 ----
  if (gi < 16512) {
    int c4 = gi & 7, ci = gi >> 3;
    int b = ci / 516, cell = ci - b * 516;
    int row, col;
    if (cell < 130)      { row = 0;   col = cell; }
    else if (cell < 260) { row = 129; col = cell - 130; }
    else { int k = cell - 260; row = 1 + (k >> 1); col = (k & 1) ? 129 : 0; }
    reinterpret_cast<int4*>(xt_u32 + ((size_t)(b * PW + row) * PW + col) * 32)[c4] =
        make_int4(0, 0, 0, 0);
  }

  // ---- transpose (r8-verified) ----
  int h = blk & 127, b = blk >> 7;
  int w0 = tid & 127, ch = tid >> 7;
  const float* xb = x + ((size_t)b * 64 * HW + h) * HW;
#pragma unroll
  for (int k = 0; k < 32; ++k) {
    int c = ch * 32 + k;
    tile[c * 129 + (w0 ^ (c & 1))] = xb[c * (HW * HW) + w0];
  }
  __syncthreads();
  int c2 = tid & 31, wg = tid >> 5;
#pragma unroll
  for (int k = 0; k < 16; ++k) {
    int ww = wg * 16 + k;
    float lo = tile[(2 * c2) * 129 + ww];
    float hi = tile[(2 * c2 + 1) * 129 + (ww ^ 1)];
    xt_u32[((size_t)(b * PW + h + 1) * PW + (ww + 1)) * 32 + c2] =
        (unsigned int)f2bf(lo) | ((unsigned int)f2bf(hi) << 16);
  }
}

// ---------------- k_fuse: offsets-MFMA (phase 0) + gather + main MFMA GEMM ----------------
// LDS union: phase 0 uses [0,25344) as the 3x66x64 slab; main loop uses
// [0,8192)x2 = ldsA dbuf, [16384,24576)x2 = ldsB dbuf. loff is separate.
__global__ __launch_bounds__(256) void k_fuse(const unsigned short* __restrict__ xt,
                                              const unsigned short* __restrict__ wb,
                                              const unsigned short* __restrict__ wtbs,
                                              const float* __restrict__ b_off,
                                              const float* __restrict__ bias,
                                              float* __restrict__ out) {
  __shared__ __align__(16) char u_lds[32768];
  __shared__ __align__(16) float loff[64 * 18];

  int bid = blockIdx.x;
  bid = (bid & 7) * 128 + (bid >> 3);     // XCD swizzle (1024 % 8 == 0)
  int pix0 = bid * 64;
  int h = (pix0 >> 7) & 127, b = pix0 >> 14, wbase = pix0 & 127;

  int tid = threadIdx.x;
  int wid = tid >> 6, lane = tid & 63;
  int l15 = lane & 15, l4 = lane >> 4;
  int wm = wid >> 1, wn = wid & 1;
  int g = tid & 7, p2 = tid >> 3;

  const unsigned short* xb  = xt + (size_t)b * (PW * PW * 64);
  const unsigned short* xtb = xb + g * 8;
  unsigned short* slabA = (unsigned short*)u_lds;

  // ======== phase 0: offsets conv (r8 k_offm, output -> loff) ========
  for (int i = wid; i < 25; i += 4) {
    int e = i * 512 + lane * 8;
    if (e < 12672) {
      int S = e >> 6, c8 = (e >> 3) & 7;
      int r = S / 66, u = S - r * 66;
      gld_lds16(xb + ((size_t)((h + r) * PW + wbase + u)) * 64 + ((c8 ^ (S & 7)) << 3),
                &slabA[i * 512]);
    }
  }

  const int4* wb4 = reinterpret_cast<const int4*>(wb);
  int4 bc[4], bn[4];
#pragma unroll
  for (int q = 0; q < 4; ++q) bc[q] = wb4[q * 64 + lane];   // tap 0 frags
  asm volatile("s_waitcnt vmcnt(0)" ::: "memory");
  __builtin_amdgcn_s_barrier();

  f32x4 acc0 = {0.f, 0.f, 0.f, 0.f}, acc1 = {0.f, 0.f, 0.f, 0.f};
#pragma unroll 1
  for (int t = 0; t < 9; ++t) {
    if (t < 8) {
#pragma unroll
      for (int q = 0; q < 4; ++q) bn[q] = wb4[((t + 1) * 4 + q) * 64 + lane];
    }
    int ti = t / 3, tj = t - ti * 3;
    int S = ti * 66 + wid * 16 + l15 + tj;
#pragma unroll
    for (int kk = 0; kk < 2; ++kk) {
      int phys = (kk * 4 + l4) ^ (S & 7);
      bf16x8 a = *reinterpret_cast<const bf16x8*>(
          reinterpret_cast<const char*>(slabA) + S * 128 + phys * 16);
      acc0 = __builtin_amdgcn_mfma_f32_16x16x32_bf16(a, *(const bf16x8*)&bc[kk * 2 + 0], acc0, 0, 0, 0);
      acc1 = __builtin_amdgcn_mfma_f32_16x16x32_bf16(a, *(const bf16x8*)&bc[kk * 2 + 1], acc1, 0, 0, 0);
    }
#pragma unroll
    for (int q = 0; q < 4; ++q) bc[q] = bn[q];
  }

  // D layout: col=l15 -> oc, row=(l4*4+reg) -> pixel (within wid's 16-pixel group)
  {
    float bo0 = b_off[l15];
    int pl = wid * 16 + l4 * 4;
#pragma unroll
    for (int reg = 0; reg < 4; ++reg)
      loff[(pl + reg) * 18 + l15] = acc0[reg] + bo0;
    if (l15 < 2) {
      float bo1 = b_off[16 + l15];
#pragma unroll
      for (int reg = 0; reg < 4; ++reg)
        loff[(pl + reg) * 18 + 16 + l15] = acc1[reg] + bo1;
    }
  }
  __syncthreads();   // slab reads done (union about to be overwritten) + loff visible

  // ======== phases 1..9: gather + GEMM (r8 k_fuse, loff already in LDS) ========
  auto ldsAp = [&](int s) { return (unsigned short*)(u_lds + s * 8192); };
  auto ldsBp = [&](int s) { return (unsigned short*)(u_lds + 16384 + s * 8192); };

  auto stageB = [&](int t, int bsel) {
#pragma unroll
    for (int j = 0; j < 2; ++j) {
      int instr = j * 4 + wid;
      int cg = instr * 64 + lane;
      int row = cg >> 3, c8 = cg & 7;
      gld_lds16(wtbs + ((size_t)(t * 64 + row) * 64 + c8 * 8),
                ldsBp(bsel) + instr * 512);
    }
  };

  int4 r[2][4];
  float fw[2][4];

  auto issue_gather = [&](int t) {
    int ti = t / 3, tj = t % 3;
#pragma unroll
    for (int k = 0; k < 2; ++k) {
      int pp = p2 + 32 * k;
      float2 d = *reinterpret_cast<const float2*>(&loff[pp * 18 + 2 * t]);
      float py = (float)(h + ti - 1) + d.x;
      float px = (float)(wbase + pp + tj - 1) + d.y;
      float y0f = floorf(py), x0f = floorf(px);
      float wy = py - y0f, wxf = px - x0f;
      int y0 = (int)y0f, x0 = (int)x0f;
      int y1 = y0 + 1, x1 = x0 + 1;
      fw[k][0] = (((unsigned)y0 < HW) && ((unsigned)x0 < HW)) ? (1.f - wy) * (1.f - wxf) : 0.f;
      fw[k][1] = (((unsigned)y0 < HW) && ((unsigned)x1 < HW)) ? (1.f - wy) * wxf : 0.f;
      fw[k][2] = (((unsigned)y1 < HW) && ((unsigned)x0 < HW)) ? wy * (1.f - wxf) : 0.f;
      fw[k][3] = (((unsigned)y1 < HW) && ((unsigned)x1 < HW)) ? wy * wxf : 0.f;
      int y0c = min(max(y0, 0), HW - 1) + 1, y1c = min(max(y1, 0), HW - 1) + 1;
      int x0c = min(max(x0, 0), HW - 1) + 1, x1c = min(max(x1, 0), HW - 1) + 1;
      r[k][0] = *reinterpret_cast<const int4*>(xtb + ((size_t)y0c * PW + x0c) * 64);
      r[k][1] = *reinterpret_cast<const int4*>(xtb + ((size_t)y0c * PW + x1c) * 64);
      r[k][2] = *reinterpret_cast<const int4*>(xtb + ((size_t)y1c * PW + x0c) * 64);
      r[k][3] = *reinterpret_cast<const int4*>(xtb + ((size_t)y1c * PW + x1c) * 64);
    }
  };

  auto lerp_write = [&](int bsel) {
#pragma unroll
    for (int k = 0; k < 2; ++k) {
      int pp = p2 + 32 * k;
      float v00[8], v01[8], v10[8], v11[8];
      bf8_to_f32(r[k][0], v00); bf8_to_f32(r[k][1], v01);
      bf8_to_f32(r[k][2], v10); bf8_to_f32(r[k][3], v11);
      unsigned int pk[4];
#pragma unroll
      for (int j = 0; j < 4; ++j) {
        float slo = fmaf(v11[2 * j], fw[k][3],
                    fmaf(v10[2 * j], fw[k][2],
                    fmaf(v01[2 * j], fw[k][1], v00[2 * j] * fw[k][0])));
        float shi = fmaf(v11[2 * j + 1], fw[k][3],
                    fmaf(v10[2 * j + 1], fw[k][2],
                    fmaf(v01[2 * j + 1], fw[k][1], v00[2 * j + 1] * fw[k][0])));
        pk[j] = (unsigned int)f2bf(slo) | ((unsigned int)f2bf(shi) << 16);
      }
      *reinterpret_cast<int4*>(&ldsAp(bsel)[pp * 64 + ((g ^ (pp & 7)) << 3)]) =
          *reinterpret_cast<int4*>(pk);
    }
  };

  f32x4 acc00 = {0.f, 0.f, 0.f, 0.f}, acc01 = {0.f, 0.f, 0.f, 0.f};
  f32x4 acc10 = {0.f, 0.f, 0.f, 0.f}, acc11 = {0.f, 0.f, 0.f, 0.f};

  stageB(0, 0);
  issue_gather(0);
  lerp_write(0);
  asm volatile("s_waitcnt vmcnt(0)" ::: "memory");
  __syncthreads();                 // A0, B0 ready

#pragma unroll 1
  for (int t = 0; t < 9; ++t) {
    int cur = t & 1;
    if (t < 8) {
      stageB(t + 1, cur ^ 1);
      issue_gather(t + 1);
    }
    const char* Ab = (const char*)ldsAp(cur);
    const char* Bb = (const char*)ldsBp(cur);
#pragma unroll
    for (int kk = 0; kk < 2; ++kk) {
      int sw = (((kk * 4 + l4) ^ (l15 & 7)) << 4) + l15 * 128;
      bf16x8 a0 = *(const bf16x8*)(Ab + (wm * 32 + 0)  * 128 + sw);
      bf16x8 a1 = *(const bf16x8*)(Ab + (wm * 32 + 16) * 128 + sw);
      bf16x8 b0 = *(const bf16x8*)(Bb + (wn * 32 + 0)  * 128 + sw);
      bf16x8 b1 = *(const bf16x8*)(Bb + (wn * 32 + 16) * 128 + sw);
      acc00 = __builtin_amdgcn_mfma_f32_16x16x32_bf16(a0, b0, acc00, 0, 0, 0);
      acc01 = __builtin_amdgcn_mfma_f32_16x16x32_bf16(a0, b1, acc01, 0, 0, 0);
      acc10 = __builtin_amdgcn_mfma_f32_16x16x32_bf16(a1, b0, acc10, 0, 0, 0);
      acc11 = __builtin_amdgcn_mfma_f32_16x16x32_bf16(a1, b1, acc11, 0, 0, 0);
    }
    if (t < 8) lerp_write(cur ^ 1);
    asm volatile("s_waitcnt vmcnt(0)" ::: "memory");
    __syncthreads();
  }

  int m0 = wm * 32 + (l4 << 2);
#pragma unroll
  for (int fm = 0; fm < 2; ++fm) {
#pragma unroll
    for (int fn = 0; fn < 2; ++fn) {
      f32x4 a = (fm == 0) ? ((fn == 0) ? acc00 : acc01) : ((fn == 0) ? acc10 : acc11);
      int o = wn * 32 + fn * 16 + l15;
      int pix = pix0 + m0 + fm * 16;
      int bb = pix >> 14, hw = pix & 16383;
      float bz = bias[o];
      float4 st = make_float4(a[0] + bz, a[1] + bz, a[2] + bz, a[3] + bz);
      *reinterpret_cast<float4*>(&out[(((size_t)bb * 64 + o) << 14) + hw]) = st;
    }
  }
}

extern "C" void kernel_launch(void* const* d_in, const int* in_sizes, int n_in,
                              void* d_out, int out_size, void* d_ws, size_t ws_size,
                              hipStream_t stream) {
  const float* x     = (const float*)d_in[0];
  const float* w_off = (const float*)d_in[1];
  const float* b_off = (const float*)d_in[2];
  const float* w     = (const float*)d_in[3];
  const float* bias  = (const float*)d_in[4];
  float* out = (float*)d_out;
  char* ws   = (char*)d_ws;

  // ws layout (BYTES):
  //   wtbs [0,       73,728)      36,864 bf16 (main-GEMM B, swizzled)
  //   wb   [73,728,  110,592)     18,432 bf16 (offsets-conv B frags)
  //   xt   [110,592, 8,763,392)   4*130*130*64 bf16 (padded, zero border)
  unsigned short* wtbs = (unsigned short*)(ws);
  unsigned short* wb   = (unsigned short*)(ws + 73728);
  unsigned short* xt   = (unsigned short*)(ws + 110592);

  hipLaunchKernelGGL(k_tr,   dim3(512),  dim3(256), 0, stream,
                     x, (unsigned int*)xt, w, w_off, wtbs, wb);
  hipLaunchKernelGGL(k_fuse, dim3(1024), dim3(256), 0, stream,
                     xt, wb, wtbs, b_off, bias, out);
}